// Round 1
// baseline (855.745 us; speedup 1.0000x reference)
//
#include <hip/hip_runtime.h>
#include <hip/hip_bf16.h>

// KVMem: 8-head attention, Lq=1024, Z=32768, hd=128, no 1/sqrt(d) scaling.
// Flash-style with z-split partials + combine. bf16 MFMA 16x16x32, fp32 acc.

#define NH 8
#define HD 128
#define LQ 1024
#define ZTOT 32768
#define ZSPLIT 4
#define ZCHUNK (ZTOT / ZSPLIT)   // 8192
#define ZSTEP 64
#define MQ 128                   // q rows per block
#define QT (LQ / MQ)             // 8 q-tiles per head
#define LOG2E 1.44269504088896f

typedef __bf16 bf16x8 __attribute__((ext_vector_type(8)));
typedef float f32x4 __attribute__((ext_vector_type(4)));

// LDS layout (single-buffered, 48 KB):
//   K tile  [64 z][128 d] bf16, XOR-swizzled:  byte = z*256 + d*2  ^ ((z&7)<<4)
//   V tile  [128 d][64 z] bf16, XOR-swizzled:  byte = d*128 + z*2  ^ ((d&7)<<4)
//   P tiles [8 waves][16 r][64 z] bf16:        byte = r*128 + z*2  ^ ((r&7)<<4)
#define K_BASE 0
#define V_BASE 16384
#define P_BASE 32768

__device__ __forceinline__ bf16x8 to_bf8(float4 a, float4 b) {
    bf16x8 r;
    r[0] = (__bf16)a.x; r[1] = (__bf16)a.y; r[2] = (__bf16)a.z; r[3] = (__bf16)a.w;
    r[4] = (__bf16)b.x; r[5] = (__bf16)b.y; r[6] = (__bf16)b.z; r[7] = (__bf16)b.w;
    return r;
}

__global__ __launch_bounds__(512) void kvmem_flash(
    const float* __restrict__ hin, const float* __restrict__ kw,
    const float* __restrict__ vw, float* __restrict__ Opart,
    float* __restrict__ Mpart, float* __restrict__ Lpart)
{
    __shared__ __align__(16) unsigned char smem[49152];

    const int bid  = blockIdx.x;
    const int head = bid >> 5;          // 32 blocks per head
    const int zs   = (bid >> 3) & 3;
    const int qt   = bid & 7;
    const int tid  = threadIdx.x;
    const int wv   = tid >> 6;
    const int ln   = tid & 63;
    const int l15  = ln & 15;
    const int lg   = ln >> 4;

    const int zbase0 = zs * ZCHUNK;
    const int qrow0  = qt * MQ;

    // ---- Q fragments in registers: wave owns 16 rows, k = d (128) in 4 frags
    bf16x8 qf[4];
    {
        const float* qsrc = hin + (size_t)(qrow0 + wv * 16 + l15) * 1024 + head * HD;
        #pragma unroll
        for (int kf = 0; kf < 4; ++kf) {
            const float4* p4 = reinterpret_cast<const float4*>(qsrc + kf * 32 + lg * 8);
            qf[kf] = to_bf8(p4[0], p4[1]);
        }
    }

    f32x4 oacc[8];
    #pragma unroll
    for (int i = 0; i < 8; ++i) oacc[i] = f32x4{0.f, 0.f, 0.f, 0.f};
    float mrow[4], lrow[4];
    #pragma unroll
    for (int r = 0; r < 4; ++r) { mrow[r] = -1e30f; lrow[r] = 0.f; }

    const unsigned pbase = P_BASE + wv * 2048;

    for (int zb = 0; zb < ZCHUNK; zb += ZSTEP) {
        __syncthreads();   // all waves done reading previous K/V tile

        // ---- stage K tile: 64 z x 128 d  (1024 chunks of 8 elems)
        #pragma unroll
        for (int pp = 0; pp < 2; ++pp) {
            int c = tid + pp * 512;
            int z = c >> 4, dc = c & 15;
            const float4* src = reinterpret_cast<const float4*>(
                kw + (size_t)(zbase0 + zb + z) * 1024 + head * HD + dc * 8);
            unsigned byte = (unsigned)(z * 256 + dc * 16) ^ ((unsigned)(z & 7) << 4);
            *(bf16x8*)(smem + K_BASE + byte) = to_bf8(src[0], src[1]);
        }
        // ---- stage V tile (transposed layout): 128 d x 64 z
        #pragma unroll
        for (int pp = 0; pp < 2; ++pp) {
            int c = tid + pp * 512;
            int d = c >> 3, zc = c & 7;
            const float4* src = reinterpret_cast<const float4*>(
                vw + (size_t)(head * HD + d) * 32768 + zbase0 + zb + zc * 8);
            unsigned byte = (unsigned)(d * 128 + zc * 16) ^ ((unsigned)(d & 7) << 4);
            *(bf16x8*)(smem + V_BASE + byte) = to_bf8(src[0], src[1]);
        }
        __syncthreads();

        // ---- QK^T: S[16 rows x 64 z]
        f32x4 sf[4];
        #pragma unroll
        for (int cf = 0; cf < 4; ++cf) sf[cf] = f32x4{0.f, 0.f, 0.f, 0.f};
        #pragma unroll
        for (int kf = 0; kf < 4; ++kf) {
            #pragma unroll
            for (int cf = 0; cf < 4; ++cf) {
                int z = cf * 16 + l15;
                unsigned byte = (unsigned)(z * 256 + (kf * 32 + lg * 8) * 2)
                                ^ ((unsigned)(z & 7) << 4);
                bf16x8 b = *(const bf16x8*)(smem + K_BASE + byte);
                sf[cf] = __builtin_amdgcn_mfma_f32_16x16x32_bf16(qf[kf], b, sf[cf], 0, 0, 0);
            }
        }

        // ---- online softmax (rows live on 16-lane groups; reduce over l&15)
        float scale[4], psum[4];
        #pragma unroll
        for (int r = 0; r < 4; ++r) {
            float mx = fmaxf(fmaxf(sf[0][r], sf[1][r]), fmaxf(sf[2][r], sf[3][r]));
            #pragma unroll
            for (int msk = 1; msk < 16; msk <<= 1) mx = fmaxf(mx, __shfl_xor(mx, msk, 16));
            float mn = fmaxf(mrow[r], mx);
            scale[r] = exp2f((mrow[r] - mn) * LOG2E);
            mrow[r] = mn;
            psum[r] = 0.f;
        }
        #pragma unroll
        for (int cf = 0; cf < 4; ++cf) {
            #pragma unroll
            for (int r = 0; r < 4; ++r) {
                float p = exp2f((sf[cf][r] - mrow[r]) * LOG2E);
                psum[r] += p;
                int row = lg * 4 + r;
                unsigned byte = (unsigned)(row * 128 + (cf * 16 + l15) * 2)
                                ^ ((unsigned)(row & 7) << 4);
                *(__bf16*)(smem + pbase + byte) = (__bf16)p;
            }
        }
        #pragma unroll
        for (int r = 0; r < 4; ++r) {
            float s = psum[r];
            #pragma unroll
            for (int msk = 1; msk < 16; msk <<= 1) s += __shfl_xor(s, msk, 16);
            lrow[r] = lrow[r] * scale[r] + s;
        }
        #pragma unroll
        for (int df = 0; df < 8; ++df) {
            #pragma unroll
            for (int r = 0; r < 4; ++r) oacc[df][r] *= scale[r];
        }

        // ---- PV: O[16 rows x 128 d] += P[16 x 64] * V^T[64 x 128]
        #pragma unroll
        for (int kf2 = 0; kf2 < 2; ++kf2) {
            unsigned abyte = (unsigned)(l15 * 128 + (kf2 * 32 + lg * 8) * 2)
                             ^ ((unsigned)(l15 & 7) << 4);
            bf16x8 pa = *(const bf16x8*)(smem + pbase + abyte);
            #pragma unroll
            for (int df = 0; df < 8; ++df) {
                int d = df * 16 + l15;
                unsigned byte = (unsigned)(d * 128 + (kf2 * 32 + lg * 8) * 2)
                                ^ ((unsigned)(d & 7) << 4);
                bf16x8 vb = *(const bf16x8*)(smem + V_BASE + byte);
                oacc[df] = __builtin_amdgcn_mfma_f32_16x16x32_bf16(pa, vb, oacc[df], 0, 0, 0);
            }
        }
    }

    // ---- epilogue: unnormalized partials + stats
    const int sb = (zs * NH + head) * LQ;
    #pragma unroll
    for (int df = 0; df < 8; ++df) {
        #pragma unroll
        for (int r = 0; r < 4; ++r) {
            int row = qrow0 + wv * 16 + lg * 4 + r;
            Opart[(size_t)(sb + row) * HD + df * 16 + l15] = oacc[df][r];
        }
    }
    if (l15 == 0) {
        #pragma unroll
        for (int r = 0; r < 4; ++r) {
            int row = qrow0 + wv * 16 + lg * 4 + r;
            Mpart[sb + row] = mrow[r];
            Lpart[sb + row] = lrow[r];
        }
    }
}

__global__ __launch_bounds__(128) void kvmem_combine(
    const float* __restrict__ Opart, const float* __restrict__ Mpart,
    const float* __restrict__ Lpart, float* __restrict__ out)
{
    const int bid  = blockIdx.x;       // NH*LQ = 8192
    const int head = bid >> 10;
    const int row  = bid & 1023;
    const int d    = threadIdx.x;

    float m[ZSPLIT];
    float M = -1e30f;
    #pragma unroll
    for (int z = 0; z < ZSPLIT; ++z) {
        m[z] = Mpart[(z * NH + head) * LQ + row];
        M = fmaxf(M, m[z]);
    }
    float L = 0.f, o = 0.f;
    #pragma unroll
    for (int z = 0; z < ZSPLIT; ++z) {
        float w = exp2f((m[z] - M) * LOG2E);
        L += w * Lpart[(z * NH + head) * LQ + row];
        o += w * Opart[(size_t)((z * NH + head) * LQ + row) * HD + d];
    }
    out[(size_t)row * 1024 + head * HD + d] = o / L;
}

extern "C" void kernel_launch(void* const* d_in, const int* in_sizes, int n_in,
                              void* d_out, int out_size, void* d_ws, size_t ws_size,
                              hipStream_t stream) {
    const float* hin = (const float*)d_in[0];   // [1024, 1024]
    const float* kw  = (const float*)d_in[1];   // [32768, 1024]
    const float* vw  = (const float*)d_in[2];   // [1024, 32768]
    float* out = (float*)d_out;                 // [1024, 1024]

    float* Opart = (float*)d_ws;                          // 4*8*1024*128 f32 = 16 MB
    float* Mpart = Opart + (size_t)ZSPLIT * NH * LQ * HD; // 32K f32
    float* Lpart = Mpart + ZSPLIT * NH * LQ;              // 32K f32

    kvmem_flash<<<dim3(NH * QT * ZSPLIT), dim3(512), 0, stream>>>(
        hin, kw, vw, Opart, Mpart, Lpart);
    kvmem_combine<<<dim3(NH * LQ), dim3(HD), 0, stream>>>(Opart, Mpart, Lpart, out);
}

// Round 2
// 782.065 us; speedup vs baseline: 1.0942x; 1.0942x over previous
//
#include <hip/hip_runtime.h>
#include <hip/hip_bf16.h>

// KVMem: 8-head attention, Lq=1024, Z=32768, hd=128, no 1/sqrt(d) scaling.
// Flash-style with z-split partials + combine. bf16 MFMA 16x16x32, fp32 acc.
// R2: double-buffered K/V LDS + early global-load issue (1 barrier/iter),
//     XCD-aware swizzle so chunk-sharing blocks co-reside on one XCD's L2.

#define NH 8
#define HD 128
#define LQ 1024
#define ZTOT 32768
#define ZSPLIT 4
#define ZCHUNK (ZTOT / ZSPLIT)   // 8192
#define ZSTEP 64
#define NT (ZCHUNK / ZSTEP)      // 128 iterations
#define MQ 128                   // q rows per block
#define QT (LQ / MQ)             // 8 q-tiles per head
#define LOG2E 1.44269504088896f

typedef __bf16 bf16x8 __attribute__((ext_vector_type(8)));
typedef float f32x4 __attribute__((ext_vector_type(4)));

// LDS layout (double-buffered K/V, 80 KB):
//   buf b: K at b*32768        [64 z][128 d] bf16, byte = z*256 + d*2 ^ ((z&7)<<4)
//          V at b*32768+16384  [128 d][64 z] bf16, byte = d*128 + z*2 ^ ((d&7)<<4)
//   P tiles at 65536: [8 waves][16 r][64 z] bf16,  byte = r*128 + z*2 ^ ((r&7)<<4)
#define KB(b) ((b) * 32768)
#define VB(b) ((b) * 32768 + 16384)
#define P_BASE 65536

__device__ __forceinline__ bf16x8 to_bf8(float4 a, float4 b) {
    bf16x8 r;
    r[0] = (__bf16)a.x; r[1] = (__bf16)a.y; r[2] = (__bf16)a.z; r[3] = (__bf16)a.w;
    r[4] = (__bf16)b.x; r[5] = (__bf16)b.y; r[6] = (__bf16)b.z; r[7] = (__bf16)b.w;
    return r;
}

__global__ __launch_bounds__(512) void kvmem_flash(
    const float* __restrict__ hin, const float* __restrict__ kw,
    const float* __restrict__ vw, float* __restrict__ Opart,
    float* __restrict__ Mpart, float* __restrict__ Lpart)
{
    __shared__ __align__(16) unsigned char smem[81920];

    const int bid = blockIdx.x;
    // XCD co-location: all 8 qt-blocks of one (head,zs) share bid&7 -> same XCD.
    const int x    = bid & 7;
    const int qt   = (bid >> 3) & 7;
    const int ghi  = bid >> 6;           // 0..3
    const int g    = x + (ghi << 3);     // 0..31 = head*4+zs
    const int head = g >> 2;
    const int zs   = g & 3;

    const int tid = threadIdx.x;
    const int wv  = tid >> 6;
    const int ln  = tid & 63;
    const int l15 = ln & 15;
    const int lg  = ln >> 4;

    const int zbase0 = zs * ZCHUNK;
    const int qrow0  = qt * MQ;

    // staging coords (two chunks each via pp=0/1 -> +512 threads)
    const int kz = tid >> 4, kd = tid & 15;   // K: z = kz (+32), d-chunk = kd
    const int vd = tid >> 3, vz = tid & 7;    // V: d = vd (+64), z-chunk = vz
    const float* kbase = kw + (size_t)(zbase0 + kz) * 1024 + head * HD + kd * 8;
    const float* vbase = vw + (size_t)(head * HD + vd) * 32768 + zbase0 + vz * 8;

    // precomputed swizzled LDS byte offsets for staging writes
    unsigned kwb[2], vwb[2];
    #pragma unroll
    for (int pp = 0; pp < 2; ++pp) {
        int z = kz + pp * 32;
        kwb[pp] = (unsigned)(z * 256 + kd * 16) ^ ((unsigned)(z & 7) << 4);
        int d = vd + pp * 64;
        vwb[pp] = (unsigned)(d * 128 + vz * 16) ^ ((unsigned)(d & 7) << 4);
    }

    // ---- Q fragments in registers: wave owns 16 rows, k = d (128) in 4 frags
    bf16x8 qf[4];
    {
        const float* qsrc = hin + (size_t)(qrow0 + wv * 16 + l15) * 1024 + head * HD;
        #pragma unroll
        for (int kf = 0; kf < 4; ++kf) {
            const float4* p4 = reinterpret_cast<const float4*>(qsrc + kf * 32 + lg * 8);
            qf[kf] = to_bf8(p4[0], p4[1]);
        }
    }

    f32x4 oacc[8];
    #pragma unroll
    for (int i = 0; i < 8; ++i) oacc[i] = f32x4{0.f, 0.f, 0.f, 0.f};
    float mrow[4], lrow[4];
    #pragma unroll
    for (int r = 0; r < 4; ++r) { mrow[r] = -1e30f; lrow[r] = 0.f; }

    const unsigned pbase = P_BASE + wv * 2048;

    float4 kst[4], vst[4];   // staging registers (tile in flight)

    // ---- prologue: load tile 0 and commit to buf 0
    #pragma unroll
    for (int pp = 0; pp < 2; ++pp) {
        const float4* ks = reinterpret_cast<const float4*>(kbase + (size_t)pp * 32 * 1024);
        kst[2 * pp] = ks[0]; kst[2 * pp + 1] = ks[1];
        const float4* vs = reinterpret_cast<const float4*>(vbase + (size_t)pp * 64 * 32768);
        vst[2 * pp] = vs[0]; vst[2 * pp + 1] = vs[1];
    }
    #pragma unroll
    for (int pp = 0; pp < 2; ++pp) {
        *(bf16x8*)(smem + KB(0) + kwb[pp]) = to_bf8(kst[2 * pp], kst[2 * pp + 1]);
        *(bf16x8*)(smem + VB(0) + vwb[pp]) = to_bf8(vst[2 * pp], vst[2 * pp + 1]);
    }
    __syncthreads();

    for (int it = 0; it < NT; ++it) {
        const int cur = it & 1;

        // ---- issue next tile's global loads early (latency hides under compute)
        if (it + 1 < NT) {
            const size_t zo = (size_t)(it + 1) * ZSTEP;
            #pragma unroll
            for (int pp = 0; pp < 2; ++pp) {
                const float4* ks = reinterpret_cast<const float4*>(
                    kbase + (zo + pp * 32) * 1024);
                kst[2 * pp] = ks[0]; kst[2 * pp + 1] = ks[1];
                const float4* vs = reinterpret_cast<const float4*>(
                    vbase + zo + (size_t)pp * 64 * 32768);
                vst[2 * pp] = vs[0]; vst[2 * pp + 1] = vs[1];
            }
        }

        // ---- QK^T: S[16 rows x 64 z]
        f32x4 sf[4];
        #pragma unroll
        for (int cf = 0; cf < 4; ++cf) sf[cf] = f32x4{0.f, 0.f, 0.f, 0.f};
        #pragma unroll
        for (int kf = 0; kf < 4; ++kf) {
            #pragma unroll
            for (int cf = 0; cf < 4; ++cf) {
                int z = cf * 16 + l15;
                unsigned byte = (unsigned)(z * 256 + (kf * 32 + lg * 8) * 2)
                                ^ ((unsigned)(z & 7) << 4);
                bf16x8 b = *(const bf16x8*)(smem + KB(cur) + byte);
                sf[cf] = __builtin_amdgcn_mfma_f32_16x16x32_bf16(qf[kf], b, sf[cf], 0, 0, 0);
            }
        }

        // ---- online softmax (rows live on 16-lane groups; reduce over l&15)
        float scale[4], psum[4];
        #pragma unroll
        for (int r = 0; r < 4; ++r) {
            float mx = fmaxf(fmaxf(sf[0][r], sf[1][r]), fmaxf(sf[2][r], sf[3][r]));
            #pragma unroll
            for (int msk = 1; msk < 16; msk <<= 1) mx = fmaxf(mx, __shfl_xor(mx, msk, 16));
            float mn = fmaxf(mrow[r], mx);
            scale[r] = __builtin_amdgcn_exp2f((mrow[r] - mn) * LOG2E);
            mrow[r] = mn;
            psum[r] = 0.f;
        }
        #pragma unroll
        for (int cf = 0; cf < 4; ++cf) {
            #pragma unroll
            for (int r = 0; r < 4; ++r) {
                float p = __builtin_amdgcn_exp2f((sf[cf][r] - mrow[r]) * LOG2E);
                psum[r] += p;
                int row = lg * 4 + r;
                unsigned byte = (unsigned)(row * 128 + (cf * 16 + l15) * 2)
                                ^ ((unsigned)(row & 7) << 4);
                *(__bf16*)(smem + pbase + byte) = (__bf16)p;
            }
        }
        #pragma unroll
        for (int r = 0; r < 4; ++r) {
            float s = psum[r];
            #pragma unroll
            for (int msk = 1; msk < 16; msk <<= 1) s += __shfl_xor(s, msk, 16);
            lrow[r] = lrow[r] * scale[r] + s;
        }
        #pragma unroll
        for (int df = 0; df < 8; ++df) {
            #pragma unroll
            for (int r = 0; r < 4; ++r) oacc[df][r] *= scale[r];
        }

        // ---- PV: O[16 rows x 128 d] += P[16 x 64] * V^T[64 x 128]
        #pragma unroll
        for (int kf2 = 0; kf2 < 2; ++kf2) {
            unsigned abyte = (unsigned)(l15 * 128 + (kf2 * 32 + lg * 8) * 2)
                             ^ ((unsigned)(l15 & 7) << 4);
            bf16x8 pa = *(const bf16x8*)(smem + pbase + abyte);
            #pragma unroll
            for (int df = 0; df < 8; ++df) {
                int d = df * 16 + l15;
                unsigned byte = (unsigned)(d * 128 + (kf2 * 32 + lg * 8) * 2)
                                ^ ((unsigned)(d & 7) << 4);
                bf16x8 vb = *(const bf16x8*)(smem + VB(cur) + byte);
                oacc[df] = __builtin_amdgcn_mfma_f32_16x16x32_bf16(pa, vb, oacc[df], 0, 0, 0);
            }
        }

        // ---- commit next tile to the other buffer (waits vmcnt here, not earlier)
        if (it + 1 < NT) {
            #pragma unroll
            for (int pp = 0; pp < 2; ++pp) {
                *(bf16x8*)(smem + KB(cur ^ 1) + kwb[pp]) = to_bf8(kst[2 * pp], kst[2 * pp + 1]);
                *(bf16x8*)(smem + VB(cur ^ 1) + vwb[pp]) = to_bf8(vst[2 * pp], vst[2 * pp + 1]);
            }
        }
        __syncthreads();
    }

    // ---- epilogue: unnormalized partials + stats
    const int sb = (zs * NH + head) * LQ;
    #pragma unroll
    for (int df = 0; df < 8; ++df) {
        #pragma unroll
        for (int r = 0; r < 4; ++r) {
            int row = qrow0 + wv * 16 + lg * 4 + r;
            Opart[(size_t)(sb + row) * HD + df * 16 + l15] = oacc[df][r];
        }
    }
    if (l15 == 0) {
        #pragma unroll
        for (int r = 0; r < 4; ++r) {
            int row = qrow0 + wv * 16 + lg * 4 + r;
            Mpart[sb + row] = mrow[r];
            Lpart[sb + row] = lrow[r];
        }
    }
}

__global__ __launch_bounds__(128) void kvmem_combine(
    const float* __restrict__ Opart, const float* __restrict__ Mpart,
    const float* __restrict__ Lpart, float* __restrict__ out)
{
    const int bid  = blockIdx.x;       // NH*LQ = 8192
    const int head = bid >> 10;
    const int row  = bid & 1023;
    const int d    = threadIdx.x;

    float m[ZSPLIT];
    float M = -1e30f;
    #pragma unroll
    for (int z = 0; z < ZSPLIT; ++z) {
        m[z] = Mpart[(z * NH + head) * LQ + row];
        M = fmaxf(M, m[z]);
    }
    float L = 0.f, o = 0.f;
    #pragma unroll
    for (int z = 0; z < ZSPLIT; ++z) {
        float w = __builtin_amdgcn_exp2f((m[z] - M) * LOG2E);
        L += w * Lpart[(z * NH + head) * LQ + row];
        o += w * Opart[(size_t)((z * NH + head) * LQ + row) * HD + d];
    }
    out[(size_t)row * 1024 + head * HD + d] = o / L;
}

extern "C" void kernel_launch(void* const* d_in, const int* in_sizes, int n_in,
                              void* d_out, int out_size, void* d_ws, size_t ws_size,
                              hipStream_t stream) {
    const float* hin = (const float*)d_in[0];   // [1024, 1024]
    const float* kw  = (const float*)d_in[1];   // [32768, 1024]
    const float* vw  = (const float*)d_in[2];   // [1024, 32768]
    float* out = (float*)d_out;                 // [1024, 1024]

    float* Opart = (float*)d_ws;                          // 4*8*1024*128 f32 = 16 MB
    float* Mpart = Opart + (size_t)ZSPLIT * NH * LQ * HD; // 32K f32
    float* Lpart = Mpart + ZSPLIT * NH * LQ;              // 32K f32

    kvmem_flash<<<dim3(NH * QT * ZSPLIT), dim3(512), 0, stream>>>(
        hin, kw, vw, Opart, Mpart, Lpart);
    kvmem_combine<<<dim3(NH * LQ), dim3(HD), 0, stream>>>(Opart, Mpart, Lpart, out);
}